// Round 5
// baseline (2689.353 us; speedup 1.0000x reference)
//
#include <hip/hip_runtime.h>

// ---------------------------------------------------------------------------
// BidirectionalMLP equilibrium relaxation on MI355X.
// s1,s2: [256,4096], s3: [256,10].  25 steps of:
//   s1' = clip(0.5*s1 + CC + 0.25*(r2@bw1))          CC = 0.25*(rx@fw0), const
//   s2' = clip(0.5*s2 + 0.25*(r1@fw1) + 0.25*(r3@bw2))
//   s3' = clip((0.5-beta)*s3 + 0.5*(r2@fw2) + beta*y)
// Round 5: direct-from-L2 streaming GEMM (no LDS staging, no hot-loop
// barriers). Per-wave 64x32 tile, K/4 per wave (kb=wave*1024), 32 k-steps of
// [6 dwordx4 loads + 8 MFMA], double-buffered, imm-offset addressing.
// Grid exactly 1024 = 4 blocks/CU (16 waves/CU). Cross-wave K-reduce via
// 36KB LDS. s3 via per-block K-slivers + fp32 atomics into rotating 3-buffer
// accumulator (consumers clamp on read).
// ---------------------------------------------------------------------------

typedef __attribute__((ext_vector_type(4))) float f32x4;
typedef __attribute__((ext_vector_type(8))) short short8;
typedef __attribute__((ext_vector_type(4))) unsigned short us4;

__device__ __forceinline__ unsigned short f2b(float f) {
    union { float f; unsigned int u; } v;
    v.f = f;
    unsigned int r = v.u + 0x7fffu + ((v.u >> 16) & 1u);
    return (unsigned short)(r >> 16);
}

__device__ __forceinline__ float clamp01(float v) {
    return fminf(fmaxf(v, 0.0f), 1.0f);
}

// One relaxation step. Grid = 1024 x 256 threads.
//  b <  512: GEMM1 (A=R2old, B=B1T) -> S1/R1; + s3 K-sliver; + zero s3next
//  b >= 512: GEMM2 (A=R1old, B=B2T) -> S2/R2 (+rank-10 r3@bw2); + s3 affine
__global__ __launch_bounds__(256, 4) void step_kernel(
    const unsigned short* __restrict__ R2old,
    const unsigned short* __restrict__ R1old,
    const float* __restrict__ S1old, const float* __restrict__ S2old,
    float* __restrict__ S1new, float* __restrict__ S2new,
    unsigned short* __restrict__ R1new, unsigned short* __restrict__ R2new,
    const unsigned short* __restrict__ B1T, const unsigned short* __restrict__ B2T,
    const unsigned short* __restrict__ FW2T,
    const float* __restrict__ CC, const float* __restrict__ bw2,
    const float* __restrict__ y,
    const float* __restrict__ s3prev, float* __restrict__ s3cur,
    float* __restrict__ s3next, float beta)
{
    __shared__ __align__(16) float red[4][64 * 36];

    const int tid = threadIdx.x, b = blockIdx.x;
    const bool g1 = (b < 512);
    const int bb = g1 ? b : (b - 512);
    const int mt = bb >> 7, nt = bb & 127;        // 4 x 128 tiles of 64x32
    const int M0 = mt << 6, N0 = nt << 5;
    const unsigned short* __restrict__ A  = g1 ? R2old : R1old;
    const unsigned short* __restrict__ BT = g1 ? B1T : B2T;
    const int wave = tid >> 6, lane = tid & 63, fr = lane & 15, fq = lane >> 4;
    const int kb = wave << 10;                    // K-quarter base

    // 6 base pointers; all hot-loop loads use immediate offsets (ks*64B)
    const unsigned short* pA[4];
    const unsigned short* pB[2];
#pragma unroll
    for (int m = 0; m < 4; ++m)
        pA[m] = A + (size_t)(M0 + 16 * m + fr) * 4096 + kb + fq * 8;
#pragma unroll
    for (int n = 0; n < 2; ++n)
        pB[n] = BT + (size_t)(N0 + 16 * n + fr) * 4096 + kb + fq * 8;

    f32x4 acc[8];
#pragma unroll
    for (int i = 0; i < 8; ++i) acc[i] = (f32x4){0.f, 0.f, 0.f, 0.f};

    short8 a[2][4], bf[2][2];
#pragma unroll
    for (int m = 0; m < 4; ++m) a[0][m] = *(const short8*)(pA[m]);
#pragma unroll
    for (int n = 0; n < 2; ++n) bf[0][n] = *(const short8*)(pB[n]);

#pragma unroll
    for (int ks = 0; ks < 32; ++ks) {
        const int cur = ks & 1, nxt = cur ^ 1;
        if (ks < 31) {
#pragma unroll
            for (int m = 0; m < 4; ++m)
                a[nxt][m] = *(const short8*)(pA[m] + (ks + 1) * 32);
#pragma unroll
            for (int n = 0; n < 2; ++n)
                bf[nxt][n] = *(const short8*)(pB[n] + (ks + 1) * 32);
        }
#pragma unroll
        for (int m = 0; m < 4; ++m)
#pragma unroll
            for (int n = 0; n < 2; ++n)
                acc[m * 2 + n] = __builtin_amdgcn_mfma_f32_16x16x32_bf16(
                    a[cur][m], bf[cur][n], acc[m * 2 + n], 0, 0, 0);
    }

    // ---- s3 side work (outside hot loop) ----
    if (g1) {
        if (tid < 5) s3next[b * 5 + tid] = 0.f;   // pre-zero t+1 accumulator
        // K-sliver: this block owns k in [32*nt, 32*nt+32); owning wave does
        // 4 MFMAs vs FW2T (16 cols, rows>=10 zero-padded) and atomic-adds.
        if (wave == (nt >> 5)) {
            const int kg = nt * 32 + fq * 8;
            const short8 bs = *(const short8*)(FW2T + (size_t)fr * 4096 + kg);
#pragma unroll
            for (int m = 0; m < 4; ++m) {
                const short8 av = *(const short8*)(A + (size_t)(M0 + 16 * m + fr) * 4096 + kg);
                f32x4 p = __builtin_amdgcn_mfma_f32_16x16x32_bf16(
                    av, bs, (f32x4){0.f, 0.f, 0.f, 0.f}, 0, 0, 0);
                if (fr < 10) {
#pragma unroll
                    for (int rr = 0; rr < 4; ++rr)
                        atomicAdd(&s3cur[(M0 + 16 * m + 4 * fq + rr) * 10 + fr],
                                  0.5f * p[rr]);
                }
            }
        }
    } else {
        if (tid < 5) {                            // affine seed, 5 elems/block
            const int i = bb * 5 + tid;
            atomicAdd(&s3cur[i], (0.5f - beta) * clamp01(s3prev[i]) + beta * y[i]);
        }
    }

    // ---- cross-wave K reduction via LDS (stride 36: aligned, 2-way banks) ----
#pragma unroll
    for (int m = 0; m < 4; ++m)
#pragma unroll
        for (int n = 0; n < 2; ++n)
#pragma unroll
            for (int rr = 0; rr < 4; ++rr)
                red[wave][(16 * m + 4 * fq + rr) * 36 + 16 * n + fr] = acc[m * 2 + n][rr];
    __syncthreads();

    const int r = tid >> 2, c8 = (tid & 3) * 8;   // 64 rows x 32 cols, 8/thread
    f32x4 s0 = {0.f, 0.f, 0.f, 0.f}, s1 = {0.f, 0.f, 0.f, 0.f};
#pragma unroll
    for (int w = 0; w < 4; ++w) {
        s0 += *(const f32x4*)&red[w][r * 36 + c8];
        s1 += *(const f32x4*)&red[w][r * 36 + c8 + 4];
    }
    const int gr = M0 + r, gc = N0 + c8;
    const size_t o = (size_t)gr * 4096 + gc;

    if (g1) {
        const f32x4 so0 = *(const f32x4*)(S1old + o), so1 = *(const f32x4*)(S1old + o + 4);
        const f32x4 cc0 = *(const f32x4*)(CC + o),   cc1 = *(const f32x4*)(CC + o + 4);
        f32x4 v0, v1; us4 r0, r1;
#pragma unroll
        for (int j = 0; j < 4; ++j) {
            float x0 = clamp01(0.5f * so0[j] + cc0[j] + 0.25f * s0[j]);
            float x1 = clamp01(0.5f * so1[j] + cc1[j] + 0.25f * s1[j]);
            v0[j] = x0; v1[j] = x1; r0[j] = f2b(x0); r1[j] = f2b(x1);
        }
        *(f32x4*)(S1new + o) = v0; *(f32x4*)(S1new + o + 4) = v1;
        *(us4*)(R1new + o) = r0;   *(us4*)(R1new + o + 4) = r1;
    } else {
        f32x4 d0 = {0.f, 0.f, 0.f, 0.f}, d1 = d0;
#pragma unroll
        for (int j = 0; j < 10; ++j) {
            const float rj = clamp01(s3prev[gr * 10 + j]);
            d0 += rj * *(const f32x4*)(bw2 + (size_t)j * 4096 + gc);
            d1 += rj * *(const f32x4*)(bw2 + (size_t)j * 4096 + gc + 4);
        }
        const f32x4 so0 = *(const f32x4*)(S2old + o), so1 = *(const f32x4*)(S2old + o + 4);
        f32x4 v0, v1; us4 r0, r1;
#pragma unroll
        for (int j = 0; j < 4; ++j) {
            float x0 = clamp01(0.5f * so0[j] + 0.25f * s0[j] + 0.25f * d0[j]);
            float x1 = clamp01(0.5f * so1[j] + 0.25f * s1[j] + 0.25f * d1[j]);
            v0[j] = x0; v1[j] = x1; r0[j] = f2b(x0); r1[j] = f2b(x1);
        }
        *(f32x4*)(S2new + o) = v0; *(f32x4*)(S2new + o + 4) = v1;
        *(us4*)(R2new + o) = r0;   *(us4*)(R2new + o + 4) = r1;
    }
}

// ---------------- prep kernels ----------------
__device__ __forceinline__ void async16(const unsigned short* g, unsigned short* l) {
    __builtin_amdgcn_global_load_lds(
        (__attribute__((address_space(1))) void*)g,
        (__attribute__((address_space(3))) void*)l,
        16, 0, 0);
}

__device__ __forceinline__ short8 frag_ld(const unsigned short* lds, int row, int ksel) {
    int chunk = (row << 3) + (ksel ^ (row & 7));
    return *reinterpret_cast<const short8*>(lds + (chunk << 3));
}

__device__ __forceinline__ void gemm_core(
    const unsigned short* __restrict__ Ag,
    const unsigned short* __restrict__ Bg,
    int K, int M0, int N0,
    unsigned short* ldsA, unsigned short* ldsB,
    f32x4* acc, int tid)
{
    const int lane = tid & 63;
    const int wave = tid >> 6;
    const int wm = (wave >> 1) << 5;
    const int wn = (wave & 1) << 5;
    const int fr = lane & 15;
    const int fq = lane >> 4;
    const int nks = K >> 6;

    for (int ks = 0; ks < nks; ++ks) {
        const int k0 = ks << 6;
        __syncthreads();
#pragma unroll
        for (int r = 0; r < 2; ++r) {
            int ca = (r << 8) + tid;
            int row = ca >> 3, kcs = ca & 7;
            int kc = kcs ^ (row & 7);
            async16(Ag + (size_t)(M0 + row) * K + k0 + (kc << 3), ldsA + (ca << 3));
        }
#pragma unroll
        for (int r = 0; r < 2; ++r) {
            int cb = (r << 8) + tid;
            int row = cb >> 3, kcs = cb & 7;
            int kc = kcs ^ (row & 7);
            async16(Bg + (size_t)(N0 + row) * K + k0 + (kc << 3), ldsB + (cb << 3));
        }
        __syncthreads();
#pragma unroll
        for (int ki = 0; ki < 2; ++ki) {
            const int ksel = (ki << 2) + fq;
            short8 a0 = frag_ld(ldsA, wm + fr, ksel);
            short8 a1 = frag_ld(ldsA, wm + 16 + fr, ksel);
            short8 b0 = frag_ld(ldsB, wn + fr, ksel);
            short8 b1 = frag_ld(ldsB, wn + 16 + fr, ksel);
            acc[0] = __builtin_amdgcn_mfma_f32_16x16x32_bf16(a0, b0, acc[0], 0, 0, 0);
            acc[1] = __builtin_amdgcn_mfma_f32_16x16x32_bf16(a0, b1, acc[1], 0, 0, 0);
            acc[2] = __builtin_amdgcn_mfma_f32_16x16x32_bf16(a1, b0, acc[2], 0, 0, 0);
            acc[3] = __builtin_amdgcn_mfma_f32_16x16x32_bf16(a1, b1, acc[3], 0, 0, 0);
        }
    }
}

// CC = 0.25*(rx @ fw0). A = RX [256,1024] bf16, B = FW0T [4096,1024] bf16.
__global__ __launch_bounds__(256) void c1_kernel(
    const unsigned short* __restrict__ RX,
    const unsigned short* __restrict__ FW0T,
    float* __restrict__ CC)
{
    __shared__ __align__(16) unsigned short ldsA[64 * 64];
    __shared__ __align__(16) unsigned short ldsB[64 * 64];
    const int tid = threadIdx.x;
    const int b = blockIdx.x;
    const int mt = b >> 6, nt = b & 63;
    const int M0 = mt << 6, N0 = nt << 6;

    f32x4 acc[4];
#pragma unroll
    for (int i = 0; i < 4; ++i) acc[i] = (f32x4){0.f, 0.f, 0.f, 0.f};

    gemm_core(RX, FW0T, 1024, M0, N0, ldsA, ldsB, acc, tid);

    const int lane = tid & 63;
    const int wave = tid >> 6;
    const int wm = (wave >> 1) << 5;
    const int wn = (wave & 1) << 5;
    const int fr = lane & 15;
    const int fq = lane >> 4;
#pragma unroll
    for (int i = 0; i < 4; ++i) {
        int im = i >> 1, in_ = i & 1;
        int n = N0 + wn + (in_ << 4) + fr;
#pragma unroll
        for (int rr = 0; rr < 4; ++rr) {
            int m = M0 + wm + (im << 4) + (fq << 2) + rr;
            CC[(size_t)m * 4096 + n] = 0.25f * acc[i][rr];
        }
    }
}

// src [R][C] fp32 row-major -> dst [C][R] bf16 (dst row stride = R).
__global__ __launch_bounds__(256) void transpose_cvt(
    const float* __restrict__ src, unsigned short* __restrict__ dst,
    int R, int C)
{
    __shared__ float t[32][33];
    const int c0 = blockIdx.x << 5, r0 = blockIdx.y << 5;
    const int tx = threadIdx.x & 31, ty = threadIdx.x >> 5;
#pragma unroll
    for (int i = 0; i < 32; i += 8)
        t[ty + i][tx] = src[(size_t)(r0 + ty + i) * C + (c0 + tx)];
    __syncthreads();
#pragma unroll
    for (int i = 0; i < 32; i += 8)
        dst[(size_t)(c0 + ty + i) * R + (r0 + tx)] = f2b(t[tx][ty + i]);
}

// FW2T (16x4096, rows>=10 zero) fill, rx convert, zero-init of state buffers.
__global__ __launch_bounds__(256) void misc_init(
    const float* __restrict__ x, const float* __restrict__ fw2,
    unsigned short* __restrict__ FW2T, unsigned short* __restrict__ RX,
    float* __restrict__ S1, float* __restrict__ S2, float* __restrict__ S3A,
    unsigned short* __restrict__ R1, unsigned short* __restrict__ R2)
{
    const int stride = gridDim.x * blockDim.x;
    const int t0 = blockIdx.x * blockDim.x + threadIdx.x;
    for (int i = t0; i < 16 * 4096; i += stride) {   // FW2T[n][k] = fw2[k][n]
        int n = i >> 12, k = i & 4095;
        FW2T[i] = (n < 10) ? f2b(fw2[k * 10 + n]) : (unsigned short)0;
    }
    for (int i = t0; i < 256 * 1024; i += stride)
        RX[i] = f2b(clamp01(x[i]));
    for (int i = t0; i < 256 * 4096; i += stride) {
        S1[i] = 0.f; S2[i] = 0.f; R1[i] = 0; R2[i] = 0;
    }
    for (int i = t0; i < 3 * 2560; i += stride) S3A[i] = 0.f;
}

__global__ __launch_bounds__(256) void pack_kernel(
    const float* __restrict__ S1, const float* __restrict__ S2,
    const float* __restrict__ S3A, float* __restrict__ out)
{
    const int stride = gridDim.x * blockDim.x;
    for (int i = blockIdx.x * blockDim.x + threadIdx.x; i < 256 * 8202; i += stride) {
        int m = i / 8202, c = i - m * 8202;
        float v;
        if (c < 4096)       v = S1[(size_t)m * 4096 + c];
        else if (c < 8192)  v = S2[(size_t)m * 4096 + (c - 4096)];
        else                v = clamp01(S3A[m * 10 + (c - 8192)]);
        out[i] = v;
    }
}

extern "C" void kernel_launch(void* const* d_in, const int* in_sizes, int n_in,
                              void* d_out, int out_size, void* d_ws, size_t ws_size,
                              hipStream_t stream) {
    const float* x   = (const float*)d_in[0];
    const float* fw0 = (const float*)d_in[1];
    const float* fw1 = (const float*)d_in[2];
    const float* fw2 = (const float*)d_in[3];
    // d_in[4] = bw0 : unused by the reference
    const float* bw1 = (const float*)d_in[5];
    const float* bw2 = (const float*)d_in[6];
    const float* y   = (const float*)d_in[7];

    char* ws = (char*)d_ws;
    unsigned short* B1T  = (unsigned short*)(ws + 0);          // 4096x4096 bf16
    unsigned short* B2T  = (unsigned short*)(ws + 33554432);   // 4096x4096 bf16
    unsigned short* FW0T = (unsigned short*)(ws + 67108864);   // 4096x1024 bf16
    unsigned short* FW2T = (unsigned short*)(ws + 75497472);   // 16x4096 bf16
    unsigned short* RX   = (unsigned short*)(ws + 75628544);   // 256x1024 bf16
    float*          CC   = (float*)(ws + 76152832);            // 256x4096 f32
    float*          S1f  = (float*)(ws + 80347136);            // 2 x 256x4096 f32
    float*          S2f  = (float*)(ws + 88735744);            // 2 x 256x4096 f32
    float*          S3A  = (float*)(ws + 97124352);            // 3 x 2560 f32
    unsigned short* R1   = (unsigned short*)(ws + 97155072);   // 2 x 256x4096 bf16
    unsigned short* R2   = (unsigned short*)(ws + 101349376);  // 2 x 256x4096 bf16
    // total ~100.7 MB

    const size_t SB = 256 * 4096;
    dim3 blk(256);

    transpose_cvt<<<dim3(128, 128), blk, 0, stream>>>(bw1, B1T, 4096, 4096);
    transpose_cvt<<<dim3(128, 128), blk, 0, stream>>>(fw1, B2T, 4096, 4096);
    transpose_cvt<<<dim3(128, 32),  blk, 0, stream>>>(fw0, FW0T, 1024, 4096);
    misc_init<<<512, blk, 0, stream>>>(x, fw2, FW2T, RX,
                                       S1f, S2f, S3A, R1, R2);
    c1_kernel<<<256, blk, 0, stream>>>(RX, FW0T, CC);

    for (int t = 0; t < 25; ++t) {
        const int o = t & 1, nw = o ^ 1;
        const float beta = (t < 20) ? 0.0f : 0.5f;
        float* s3prev = S3A + ((t + 2) % 3) * 2560;
        float* s3cur  = S3A + (t % 3) * 2560;
        float* s3next = S3A + ((t + 1) % 3) * 2560;
        step_kernel<<<1024, blk, 0, stream>>>(
            R2 + o * SB, R1 + o * SB,
            S1f + o * SB, S2f + o * SB,
            S1f + nw * SB, S2f + nw * SB,
            R1 + nw * SB, R2 + nw * SB,
            B1T, B2T, FW2T, CC, bw2, y,
            s3prev, s3cur, s3next, beta);
    }

    pack_kernel<<<2048, blk, 0, stream>>>(S1f + SB, S2f + SB,
                                          S3A + (24 % 3) * 2560,
                                          (float*)d_out);
}